// Round 8
// baseline (142.990 us; speedup 1.0000x reference)
//
#include <hip/hip_runtime.h>
#include <math.h>

#define NA   21
#define NM   64
#define ND   210
#define DP   224            // padded descriptor row
#define NT   8192
#define NCH  28             // 8-wide k-chunks per descriptor row (224/8)
#define KS2  32             // stage2 K-splits (256 t each)

#define QC 0.22360679774997896f   // sqrt(5)/10
#define KE 0.016666666666666666f  // 5/(3*sig^2)

typedef short bf8 __attribute__((ext_vector_type(8)));   // 8 bf16 (4 VGPRs)
typedef float f4  __attribute__((ext_vector_type(4)));   // 4 fp32 acc

// ---- workspace layout (float offsets); bf16 arrays count elems/2 ----
// Xf/Jf  : stage1 B frags [ttile 512][kq 28][col_t 16][8 d]
// XfT/JfT: stage2 B frags [dtile 14][tq 1024][col_d 16][8 t]
// w1f/e1f: stage2 A frags [mtile 4][tq 1024][col_m 16][8 t]
// Af     : stage1 A frags [mtile 4][kq 28][col_m 16][8 d]
// Pbuf   : [2][64 m][224 d][32 ks] fp32  (ks contiguous -> trivial reduce)
#define O_XF   0u
#define O_JF   917504u
#define O_XFT  1835008u
#define O_JFT  2752512u
#define O_W1   3670016u
#define O_E1   3932160u
#define O_AF   4194304u
#define O_QG   4201472u        // qxsG fp32 [56][64][4]
#define O_NTT  4215808u        // nt [8192]
#define O_CJ   4224000u        // cJ [8192]
#define O_NX   4232192u        // [64]
#define O_ES   4232256u        // [64]
#define O_WA   4232320u        // [64]
#define O_PB   4261056u        // 917504 floats (end 5178560 = 20.7 MB)

__device__ __forceinline__ unsigned short f2bf(float f) {
    unsigned u = __float_as_uint(f);
    u += 0x7fffu + ((u >> 16) & 1u);
    return (unsigned short)(u >> 16);
}
__device__ __forceinline__ float bf2f(unsigned short h) {
    return __uint_as_float((unsigned)h << 16);
}

__device__ __forceinline__ void d_to_ij(int d, int& i, int& j) {
    int ii = (int)((1.0f + sqrtf(1.0f + 8.0f * (float)d)) * 0.5f);
    while (ii * (ii - 1) / 2 > d) --ii;
    while ((ii + 1) * ii / 2 <= d) ++ii;
    i = ii;
    j = d - ii * (ii - 1) / 2;
}

// Fused prep. Roles by blockIdx.x:
//  [0,512)    stage1-B frags + rowstats: 16 contiguous rows via LDS (coalesced)
//  [512,768)  stage2-B frags: 64 contiguous rows via LDS
//  [768,832)  geom -> Af, qxsG, nx
//  832        zero Es/Wa
__global__ __launch_bounds__(256) void k_prep(
    const float* __restrict__ Rs, const float* __restrict__ xs,
    const float* __restrict__ Jx,
    unsigned short* __restrict__ Xf, unsigned short* __restrict__ Jf,
    unsigned short* __restrict__ XfT, unsigned short* __restrict__ JfT,
    unsigned short* __restrict__ Af, float* __restrict__ qxsG,
    float* __restrict__ nx, float* __restrict__ nt, float* __restrict__ cJ,
    float* __restrict__ zbase) {
    const int b = blockIdx.x, tid = threadIdx.x;
    __shared__ float lds[64 * 210];        // 53760 B

    if (b < 512) {                         // ---- stage1-B frags + rowstats
        const int t0 = b * 16;
        const float4* sx = (const float4*)(xs + (size_t)t0 * ND);
        const float4* sj = (const float4*)(Jx + (size_t)t0 * ND);
#pragma unroll
        for (int k = 0; k < 4; ++k) {      // 840 float4 per array
            const int i = k * 256 + tid;
            if (i < 840) {
                ((float4*)lds)[i] = sx[i];
                ((float4*)(lds + 3360))[i] = sj[i];
            }
        }
        __syncthreads();
#pragma unroll
        for (int k = 0; k < 4; ++k) {      // 896 frag chunks
            const int idx = k * 256 + tid;
            if (idx < 896) {
                const int arr = idx / 448;
                const int rem = idx - arr * 448;
                const int kq = rem >> 4, colt = rem & 15;
                const float* src = lds + arr * 3360 + colt * 210;
                const float sc = arr ? 1.0f : QC;
                union { unsigned short us[8]; uint4 v; } u;
#pragma unroll
                for (int i = 0; i < 8; ++i) {
                    const int d = kq * 8 + i;
                    u.us[i] = (d < ND) ? f2bf(sc * src[d]) : (unsigned short)0;
                }
                *(uint4*)((arr ? Jf : Xf) + ((size_t)(b * NCH + kq) * 16 + colt) * 8) = u.v;
            }
        }
        // rowstats from LDS (rounded-consistent)
        const int tt = tid >> 4, l = tid & 15;
        const float* xr = lds + tt * 210;
        const float* jr = lds + 3360 + tt * 210;
        float sn = 0.0f, sc2 = 0.0f;
        for (int c = l; c < ND; c += 16) {
            float x = bf2f(f2bf(QC * xr[c]));
            float j = bf2f(f2bf(jr[c]));
            sn = fmaf(x, x, sn);
            sc2 = fmaf(x, j, sc2);
        }
#pragma unroll
        for (int off = 1; off < 16; off <<= 1) {
            sn += __shfl_xor(sn, off);
            sc2 += __shfl_xor(sc2, off);
        }
        if (l == 0) {
            nt[t0 + tt] = sn;
            cJ[t0 + tt] = sc2;
        }
    } else if (b < 768) {                  // ---- stage2-B frags
        const int bb = b - 512;
        const int arr = bb >> 7;           // 128 blocks each
        const int tpos = bb & 127;
        const int t0 = tpos * 64;
        const float4* s = (const float4*)((arr ? Jx : xs) + (size_t)t0 * ND);
#pragma unroll
        for (int k = 0; k < 14; ++k) {     // 3360 float4
            const int i = k * 256 + tid;
            if (i < 3360) ((float4*)lds)[i] = s[i];
        }
        __syncthreads();
        unsigned short* dst = arr ? JfT : XfT;
        const float sc = arr ? 1.0f : QC;
#pragma unroll
        for (int k = 0; k < 7; ++k) {      // 1792 frag chunks
            const int idx = k * 256 + tid;
            const int dtile = idx >> 7;
            const int rem = idx & 127;
            const int tql = rem >> 4, col = rem & 15;
            const int d = dtile * 16 + col;
            union { unsigned short us[8]; uint4 v; } u;
#pragma unroll
            for (int i = 0; i < 8; ++i)
                u.us[i] = (d < ND) ? f2bf(sc * lds[(tql * 8 + i) * 210 + d])
                                   : (unsigned short)0;
            *(uint4*)(dst + ((size_t)(dtile * 1024 + tpos * 8 + tql) * 16 + col) * 8) = u.v;
        }
    } else if (b < 832) {                  // ---- geom: m = b-768
        const int m = b - 768;
        float* R = lds;
        float* red = lds + 64;
        if (tid < NA * 3) R[tid] = Rs[m * NA * 3 + tid];
        __syncthreads();
        float local = 0.0f;
        if (tid < DP) {
            float vr = 0.0f;
            unsigned short hv = 0;
            if (tid < ND) {
                int i, j; d_to_ij(tid, i, j);
                float dx = R[i * 3] - R[j * 3];
                float dy = R[i * 3 + 1] - R[j * 3 + 1];
                float dz = R[i * 3 + 2] - R[j * 3 + 2];
                float v = QC / sqrtf(dx * dx + dy * dy + dz * dz);
                hv = f2bf(v);
                vr = bf2f(hv);
            }
            Af[(((m >> 4) * NCH + (tid >> 3)) * 16 + (m & 15)) * 8 + (tid & 7)] = hv;
            qxsG[(tid >> 2) * 256 + m * 4 + (tid & 3)] = vr;
            local = vr * vr;
        }
        red[tid] = local;
        __syncthreads();
        for (int s = 128; s > 0; s >>= 1) {
            if (tid < s) red[tid] += red[tid + s];
            __syncthreads();
        }
        if (tid == 0) nx[m] = red[0];
    } else {                               // ---- zero Es/Wa
        if (tid < 128) zbase[tid] = 0.0f;
    }
}

// Stage 1 (MFMA): grid 512 (1 ttile of 16 t). Wave w = mtile. A panel in regs;
// B frags contiguous coalesced 1-KB loads, depth-2 prefetch.
__global__ __launch_bounds__(256) void k_stage1(
    const unsigned short* __restrict__ Af, const unsigned short* __restrict__ Xf,
    const unsigned short* __restrict__ Jf, const float* __restrict__ nt,
    const float* __restrict__ cJ, const float* __restrict__ nx,
    unsigned short* __restrict__ w1f, unsigned short* __restrict__ e1f,
    float* __restrict__ EsAcc, float* __restrict__ Wacc) {
    const int tid = threadIdx.x;
    const int lane = tid & 63;
    const int w = tid >> 6;                // mtile
    const int col = lane & 15, quad = lane >> 4;
    const int ttile = blockIdx.x;
    __shared__ float Dw[64][17];
    __shared__ float De[64][17];

    const unsigned short* ap = Af + ((size_t)(w * NCH + quad) * 16 + col) * 8;
    const unsigned short* xp = Xf + ((size_t)(ttile * NCH + quad) * 16 + col) * 8;
    const unsigned short* jp = Jf + ((size_t)(ttile * NCH + quad) * 16 + col) * 8;

    bf8 af[7];
#pragma unroll
    for (int kc = 0; kc < 7; ++kc) af[kc] = *(const bf8*)(ap + kc * 512);

    bf8 bx[2], bj[2];
    bx[0] = *(const bf8*)xp;
    bj[0] = *(const bf8*)jp;
    bx[1] = *(const bf8*)(xp + 512);
    bj[1] = *(const bf8*)(jp + 512);

    f4 c1 = {0.f, 0.f, 0.f, 0.f};
    f4 c2 = {0.f, 0.f, 0.f, 0.f};
#pragma unroll
    for (int kc = 0; kc < 7; ++kc) {
        const int s = kc & 1;
        c1 = __builtin_amdgcn_mfma_f32_16x16x32_bf16(af[kc], bx[s], c1, 0, 0, 0);
        c2 = __builtin_amdgcn_mfma_f32_16x16x32_bf16(af[kc], bj[s], c2, 0, 0, 0);
        if (kc < 5) {
            bx[s] = *(const bf8*)(xp + (kc + 2) * 512);
            bj[s] = *(const bf8*)(jp + (kc + 2) * 512);
        }
    }

    // epilogue: lane holds D[m=w*16+quad*4+r][t=ttile*16+col]
    const int t = ttile * 16 + col;
    const float ntv = nt[t], cjv = cJ[t];
    float esA[4], wlA[4];
#pragma unroll
    for (int r = 0; r < 4; ++r) {
        const int m = w * 16 + quad * 4 + r;
        float sq = fmaxf(nx[m] - 2.0f * c1[r] + ntv, 0.0f);
        float xd = sqrtf(sq);
        float e = KE * expf(-xd);
        float dotv = c2[r] - cjv;
        float wv = e * dotv;
        float ev = e * (1.0f + xd);
        Dw[m][col] = wv;
        De[m][col] = ev;
        esA[r] = ev * dotv;
        wlA[r] = wv;
    }
    __syncthreads();
    {   // coalesced frag-layout stores: 128 chunks per array
        const int aidx = tid >> 7;
        const int c = tid & 127;
        const int mtile = c >> 5, tql = (c >> 4) & 1, colm = c & 15;
        const float* srcD = aidx ? &De[0][0] : &Dw[0][0];
        unsigned short* dst = aidx ? e1f : w1f;
        const int m = mtile * 16 + colm;
        union { unsigned short us[8]; uint4 v; } u;
#pragma unroll
        for (int i = 0; i < 8; ++i) u.us[i] = f2bf(srcD[m * 17 + tql * 8 + i]);
        const size_t off = ((size_t)(mtile * 1024 + ttile * 2 + tql) * 16 + colm) * 8;
        *(uint4*)(dst + off) = u.v;
    }
#pragma unroll
    for (int r = 0; r < 4; ++r) {
        float e = esA[r], wl = wlA[r];
#pragma unroll
        for (int off = 1; off < 16; off <<= 1) {
            e += __shfl_xor(e, off);
            wl += __shfl_xor(wl, off);
        }
        if (col == 0) {
            atomicAdd(&EsAcc[w * 16 + quad * 4 + r], e);
            atomicAdd(&Wacc[w * 16 + quad * 4 + r], wl);
        }
    }
}

// Stage 2 (MFMA): grid (14 dtiles, 32 k-splits of 256 t). Wave w = mtile.
// All four frag streams contiguous coalesced, depth-2 prefetch.
// Pbuf layout [mat][m][d][ks] -> reduction reads are contiguous.
__global__ __launch_bounds__(256) void k_stage2(
    const unsigned short* __restrict__ w1f, const unsigned short* __restrict__ e1f,
    const unsigned short* __restrict__ XfT, const unsigned short* __restrict__ JfT,
    float* __restrict__ Pbuf) {
    const int tid = threadIdx.x;
    const int lane = tid & 63;
    const int w = tid >> 6;                // mtile
    const int col = lane & 15, quad = lane >> 4;
    const int dt = blockIdx.x;
    const int by = blockIdx.y;

    const unsigned short* awp = w1f + ((size_t)(w * 1024 + by * 32 + quad) * 16 + col) * 8;
    const unsigned short* aep = e1f + ((size_t)(w * 1024 + by * 32 + quad) * 16 + col) * 8;
    const unsigned short* bxp = XfT + ((size_t)(dt * 1024 + by * 32 + quad) * 16 + col) * 8;
    const unsigned short* bjp = JfT + ((size_t)(dt * 1024 + by * 32 + quad) * 16 + col) * 8;

    bf8 aw[2], ae[2], bx[2], bj[2];
    aw[0] = *(const bf8*)awp;         ae[0] = *(const bf8*)aep;
    bx[0] = *(const bf8*)bxp;         bj[0] = *(const bf8*)bjp;
    aw[1] = *(const bf8*)(awp + 512); ae[1] = *(const bf8*)(aep + 512);
    bx[1] = *(const bf8*)(bxp + 512); bj[1] = *(const bf8*)(bjp + 512);

    f4 dA = {0.f, 0.f, 0.f, 0.f};
    f4 dB = {0.f, 0.f, 0.f, 0.f};
#pragma unroll
    for (int kk = 0; kk < 8; ++kk) {
        const int s = kk & 1;
        dA = __builtin_amdgcn_mfma_f32_16x16x32_bf16(aw[s], bx[s], dA, 0, 0, 0);
        dB = __builtin_amdgcn_mfma_f32_16x16x32_bf16(ae[s], bj[s], dB, 0, 0, 0);
        if (kk < 6) {
            aw[s] = *(const bf8*)(awp + (kk + 2) * 512);
            ae[s] = *(const bf8*)(aep + (kk + 2) * 512);
            bx[s] = *(const bf8*)(bxp + (kk + 2) * 512);
            bj[s] = *(const bf8*)(bjp + (kk + 2) * 512);
        }
    }

    // lane holds D[m=w*16+quad*4+r][d=dt*16+col]; Pbuf[((mat*64+m)*224+d)*32+by]
    float* p = Pbuf + (size_t)(dt * 16 + col) * 32 + by;
#pragma unroll
    for (int r = 0; r < 4; ++r) {
        const int m = w * 16 + quad * 4 + r;
        p[(size_t)m * 7168] = dA[r];
        p[458752u + (size_t)m * 7168] = dB[r];
    }
}

// grid 64 (m) x 256: fused ks-reduction + expand_tril + force contraction + Es
__global__ void k_final(const float* __restrict__ Rs, const float* __restrict__ qxsG,
                        const float* __restrict__ Pbuf, const float* __restrict__ EsAcc,
                        const float* __restrict__ Wacc, float* __restrict__ out) {
    int m = blockIdx.x, tid = threadIdx.x;
    __shared__ float R[NA * 3];
    __shared__ float Ff[NA][NA];
    if (tid < NA * 3) R[tid] = Rs[m * NA * 3 + tid];
    if (tid < NA) Ff[tid][tid] = 0.0f;
    __syncthreads();
    if (tid < ND) {
        const float4* p0 = (const float4*)(Pbuf + ((size_t)m * 224 + tid) * 32);
        const float4* p1 = (const float4*)(Pbuf + 458752u + ((size_t)m * 224 + tid) * 32);
        float s1 = 0.0f, s2 = 0.0f;
#pragma unroll
        for (int k = 0; k < 8; ++k) {
            const float4 a = p0[k], bv = p1[k];
            s1 += (a.x + a.y) + (a.z + a.w);
            s2 += (bv.x + bv.y) + (bv.z + bv.w);
        }
        int i, j; d_to_ij(tid, i, j);
        float dx = R[i * 3] - R[j * 3];
        float dy = R[i * 3 + 1] - R[j * 3 + 1];
        float dz = R[i * 3 + 2] - R[j * 3 + 2];
        float dist2 = dx * dx + dy * dy + dz * dz;
        float fsx = qxsG[(tid >> 2) * 256 + m * 4 + (tid & 3)] * Wacc[m] - s1 - s2;
        float f = fsx / (dist2 * sqrtf(dist2));
        Ff[i][j] = f;
        Ff[j][i] = f;
    }
    __syncthreads();
    if (tid < NA * 3) {
        int a = tid / 3, c = tid % 3;
        float s = 0.0f;
        for (int b = 0; b < NA; ++b) {
            if (b == a) continue;
            s += Ff[a][b] * (R[a * 3 + c] - R[b * 3 + c]);
        }
        out[NM + m * NA * 3 + tid] = s;
    }
    if (tid == 0) out[m] = EsAcc[m] / QC;
}

extern "C" void kernel_launch(void* const* d_in, const int* in_sizes, int n_in,
                              void* d_out, int out_size, void* d_ws, size_t ws_size,
                              hipStream_t stream) {
    const float* Rs = (const float*)d_in[0];
    const float* xs_train = (const float*)d_in[1];
    const float* Jx_alphas = (const float*)d_in[2];
    float* out = (float*)d_out;
    float* ws = (float*)d_ws;

    unsigned short* Xf  = (unsigned short*)(ws + O_XF);
    unsigned short* Jf  = (unsigned short*)(ws + O_JF);
    unsigned short* XfT = (unsigned short*)(ws + O_XFT);
    unsigned short* JfT = (unsigned short*)(ws + O_JFT);
    unsigned short* w1f = (unsigned short*)(ws + O_W1);
    unsigned short* e1f = (unsigned short*)(ws + O_E1);
    unsigned short* Af  = (unsigned short*)(ws + O_AF);
    float* qxsG  = ws + O_QG;
    float* nt    = ws + O_NTT;
    float* cJ    = ws + O_CJ;
    float* nx    = ws + O_NX;
    float* EsAcc = ws + O_ES;
    float* Wacc  = ws + O_WA;
    float* Pbuf  = ws + O_PB;

    k_prep<<<833, 256, 0, stream>>>(Rs, xs_train, Jx_alphas, Xf, Jf, XfT, JfT,
                                    Af, qxsG, nx, nt, cJ, EsAcc);
    k_stage1<<<512, 256, 0, stream>>>(Af, Xf, Jf, nt, cJ, nx, w1f, e1f, EsAcc, Wacc);
    k_stage2<<<dim3(14, KS2), 256, 0, stream>>>(w1f, e1f, XfT, JfT, Pbuf);
    k_final<<<NM, 256, 0, stream>>>(Rs, qxsG, Pbuf, EsAcc, Wacc, out);
}

// Round 9
// 92.199 us; speedup vs baseline: 1.5509x; 1.5509x over previous
//
#include <hip/hip_runtime.h>
#include <math.h>

#define NA   21
#define NM   64
#define ND   210
#define DP   224            // padded descriptor row
#define NT   8192
#define NCH  28             // 8-wide k-chunks per descriptor row (224/8)
#define KS2  32             // stage2 K-splits (256 t each)

#define QC 0.22360679774997896f   // sqrt(5)/10
#define KE 0.016666666666666666f  // 5/(3*sig^2)

typedef short bf8 __attribute__((ext_vector_type(8)));   // 8 bf16 (4 VGPRs)
typedef float f4  __attribute__((ext_vector_type(4)));   // 4 fp32 acc

// ---- workspace layout (float offsets); bf16 arrays count elems/2 ----
// Xf/Jf  : stage1 B frags [ttile 512][kq 28][col_t 16][8 d]
// XfT/JfT: stage2 B frags [dtile 14][tq 1024][col_d 16][8 t]
// w1f/e1f: stage2 A frags [mtile 4][tq 1024][col_m 16][8 t]
// Af     : stage1 A frags [mtile 4][kq 28][col_m 16][8 d]
// Pbuf   : [ks 32][mat 2][m 64][d 224] fp32 (R7-proven)
// EsPart/WaPart: [m 64][ttile 512] fp32 (contiguous per-m -> trivial reduce)
#define O_XF   0u
#define O_JF   917504u
#define O_XFT  1835008u
#define O_JFT  2752512u
#define O_W1   3670016u
#define O_E1   3932160u
#define O_AF   4194304u
#define O_QG   4201472u        // qxsG fp32 [56][64][4]
#define O_NTT  4215808u        // nt [8192]
#define O_CJ   4224000u        // cJ [8192]
#define O_NX   4232192u        // [64]
#define O_AB   4232384u        // [2][64][224] fp32 = 28672
#define O_PB   4261056u        // 917504 floats
#define O_ESP  5178560u        // [64][512]
#define O_WAP  5211328u        // [64][512] (end 5244096 = 21 MB; ws = 268 MB)

__device__ __forceinline__ unsigned short f2bf(float f) {
    unsigned u = __float_as_uint(f);
    u += 0x7fffu + ((u >> 16) & 1u);
    return (unsigned short)(u >> 16);
}
__device__ __forceinline__ float bf2f(unsigned short h) {
    return __uint_as_float((unsigned)h << 16);
}

__device__ __forceinline__ void d_to_ij(int d, int& i, int& j) {
    int ii = (int)((1.0f + sqrtf(1.0f + 8.0f * (float)d)) * 0.5f);
    while (ii * (ii - 1) / 2 > d) --ii;
    while ((ii + 1) * ii / 2 <= d) ++ii;
    i = ii;
    j = d - ii * (ii - 1) / 2;
}

// Fused prep. Roles by blockIdx.x:
//  [0,512)    stage1-B frags + rowstats: 16 contiguous rows via LDS (coalesced)
//  [512,768)  stage2-B frags: 64 contiguous rows via LDS
//  [768,832)  geom -> Af, qxsG, nx
__global__ __launch_bounds__(256) void k_prep(
    const float* __restrict__ Rs, const float* __restrict__ xs,
    const float* __restrict__ Jx,
    unsigned short* __restrict__ Xf, unsigned short* __restrict__ Jf,
    unsigned short* __restrict__ XfT, unsigned short* __restrict__ JfT,
    unsigned short* __restrict__ Af, float* __restrict__ qxsG,
    float* __restrict__ nx, float* __restrict__ nt, float* __restrict__ cJ) {
    const int b = blockIdx.x, tid = threadIdx.x;
    __shared__ float lds[64 * 210];        // 53760 B

    if (b < 512) {                         // ---- stage1-B frags + rowstats
        const int t0 = b * 16;
        const float4* sx = (const float4*)(xs + (size_t)t0 * ND);
        const float4* sj = (const float4*)(Jx + (size_t)t0 * ND);
#pragma unroll
        for (int k = 0; k < 4; ++k) {      // 840 float4 per array
            const int i = k * 256 + tid;
            if (i < 840) {
                ((float4*)lds)[i] = sx[i];
                ((float4*)(lds + 3360))[i] = sj[i];
            }
        }
        __syncthreads();
#pragma unroll
        for (int k = 0; k < 4; ++k) {      // 896 frag chunks
            const int idx = k * 256 + tid;
            if (idx < 896) {
                const int arr = idx / 448;
                const int rem = idx - arr * 448;
                const int kq = rem >> 4, colt = rem & 15;
                const float* src = lds + arr * 3360 + colt * 210;
                const float sc = arr ? 1.0f : QC;
                union { unsigned short us[8]; uint4 v; } u;
#pragma unroll
                for (int i = 0; i < 8; ++i) {
                    const int d = kq * 8 + i;
                    u.us[i] = (d < ND) ? f2bf(sc * src[d]) : (unsigned short)0;
                }
                *(uint4*)((arr ? Jf : Xf) + ((size_t)(b * NCH + kq) * 16 + colt) * 8) = u.v;
            }
        }
        // rowstats from LDS (rounded-consistent)
        const int tt = tid >> 4, l = tid & 15;
        const float* xr = lds + tt * 210;
        const float* jr = lds + 3360 + tt * 210;
        float sn = 0.0f, sc2 = 0.0f;
        for (int c = l; c < ND; c += 16) {
            float x = bf2f(f2bf(QC * xr[c]));
            float j = bf2f(f2bf(jr[c]));
            sn = fmaf(x, x, sn);
            sc2 = fmaf(x, j, sc2);
        }
#pragma unroll
        for (int off = 1; off < 16; off <<= 1) {
            sn += __shfl_xor(sn, off);
            sc2 += __shfl_xor(sc2, off);
        }
        if (l == 0) {
            nt[t0 + tt] = sn;
            cJ[t0 + tt] = sc2;
        }
    } else if (b < 768) {                  // ---- stage2-B frags
        const int bb = b - 512;
        const int arr = bb >> 7;           // 128 blocks each
        const int tpos = bb & 127;
        const int t0 = tpos * 64;
        const float4* s = (const float4*)((arr ? Jx : xs) + (size_t)t0 * ND);
#pragma unroll
        for (int k = 0; k < 14; ++k) {     // 3360 float4
            const int i = k * 256 + tid;
            if (i < 3360) ((float4*)lds)[i] = s[i];
        }
        __syncthreads();
        unsigned short* dst = arr ? JfT : XfT;
        const float sc = arr ? 1.0f : QC;
#pragma unroll
        for (int k = 0; k < 7; ++k) {      // 1792 frag chunks
            const int idx = k * 256 + tid;
            const int dtile = idx >> 7;
            const int rem = idx & 127;
            const int tql = rem >> 4, col = rem & 15;
            const int d = dtile * 16 + col;
            union { unsigned short us[8]; uint4 v; } u;
#pragma unroll
            for (int i = 0; i < 8; ++i)
                u.us[i] = (d < ND) ? f2bf(sc * lds[(tql * 8 + i) * 210 + d])
                                   : (unsigned short)0;
            *(uint4*)(dst + ((size_t)(dtile * 1024 + tpos * 8 + tql) * 16 + col) * 8) = u.v;
        }
    } else {                               // ---- geom: m = b-768
        const int m = b - 768;
        float* R = lds;
        float* red = lds + 64;
        if (tid < NA * 3) R[tid] = Rs[m * NA * 3 + tid];
        __syncthreads();
        float local = 0.0f;
        if (tid < DP) {
            float vr = 0.0f;
            unsigned short hv = 0;
            if (tid < ND) {
                int i, j; d_to_ij(tid, i, j);
                float dx = R[i * 3] - R[j * 3];
                float dy = R[i * 3 + 1] - R[j * 3 + 1];
                float dz = R[i * 3 + 2] - R[j * 3 + 2];
                float v = QC / sqrtf(dx * dx + dy * dy + dz * dz);
                hv = f2bf(v);
                vr = bf2f(hv);
            }
            Af[(((m >> 4) * NCH + (tid >> 3)) * 16 + (m & 15)) * 8 + (tid & 7)] = hv;
            qxsG[(tid >> 2) * 256 + m * 4 + (tid & 3)] = vr;
            local = vr * vr;
        }
        red[tid] = local;
        __syncthreads();
        for (int s = 128; s > 0; s >>= 1) {
            if (tid < s) red[tid] += red[tid + s];
            __syncthreads();
        }
        if (tid == 0) nx[m] = red[0];
    }
}

// Stage 1 (MFMA): grid 512 (1 ttile of 16 t). Wave w = mtile. A panel in regs;
// B frags contiguous coalesced 1-KB loads, depth-2 prefetch. NO global atomics:
// per-block Es/W partials stored to EsPart/WaPart[m][ttile].
__global__ __launch_bounds__(256) void k_stage1(
    const unsigned short* __restrict__ Af, const unsigned short* __restrict__ Xf,
    const unsigned short* __restrict__ Jf, const float* __restrict__ nt,
    const float* __restrict__ cJ, const float* __restrict__ nx,
    unsigned short* __restrict__ w1f, unsigned short* __restrict__ e1f,
    float* __restrict__ EsPart, float* __restrict__ WaPart) {
    const int tid = threadIdx.x;
    const int lane = tid & 63;
    const int w = tid >> 6;                // mtile
    const int col = lane & 15, quad = lane >> 4;
    const int ttile = blockIdx.x;
    __shared__ float Dw[64][17];
    __shared__ float De[64][17];

    const unsigned short* ap = Af + ((size_t)(w * NCH + quad) * 16 + col) * 8;
    const unsigned short* xp = Xf + ((size_t)(ttile * NCH + quad) * 16 + col) * 8;
    const unsigned short* jp = Jf + ((size_t)(ttile * NCH + quad) * 16 + col) * 8;

    bf8 af[7];
#pragma unroll
    for (int kc = 0; kc < 7; ++kc) af[kc] = *(const bf8*)(ap + kc * 512);

    bf8 bx[2], bj[2];
    bx[0] = *(const bf8*)xp;
    bj[0] = *(const bf8*)jp;
    bx[1] = *(const bf8*)(xp + 512);
    bj[1] = *(const bf8*)(jp + 512);

    f4 c1 = {0.f, 0.f, 0.f, 0.f};
    f4 c2 = {0.f, 0.f, 0.f, 0.f};
#pragma unroll
    for (int kc = 0; kc < 7; ++kc) {
        const int s = kc & 1;
        c1 = __builtin_amdgcn_mfma_f32_16x16x32_bf16(af[kc], bx[s], c1, 0, 0, 0);
        c2 = __builtin_amdgcn_mfma_f32_16x16x32_bf16(af[kc], bj[s], c2, 0, 0, 0);
        if (kc < 5) {
            bx[s] = *(const bf8*)(xp + (kc + 2) * 512);
            bj[s] = *(const bf8*)(jp + (kc + 2) * 512);
        }
    }

    // epilogue: lane holds D[m=w*16+quad*4+r][t=ttile*16+col]
    const int t = ttile * 16 + col;
    const float ntv = nt[t], cjv = cJ[t];
    float esA[4], wlA[4];
#pragma unroll
    for (int r = 0; r < 4; ++r) {
        const int m = w * 16 + quad * 4 + r;
        float sq = fmaxf(nx[m] - 2.0f * c1[r] + ntv, 0.0f);
        float xd = sqrtf(sq);
        float e = KE * expf(-xd);
        float dotv = c2[r] - cjv;
        float wv = e * dotv;
        float ev = e * (1.0f + xd);
        Dw[m][col] = wv;
        De[m][col] = ev;
        esA[r] = ev * dotv;
        wlA[r] = wv;
    }
    __syncthreads();
    {   // coalesced frag-layout stores: 128 chunks per array
        const int aidx = tid >> 7;
        const int c = tid & 127;
        const int mtile = c >> 5, tql = (c >> 4) & 1, colm = c & 15;
        const float* srcD = aidx ? &De[0][0] : &Dw[0][0];
        unsigned short* dst = aidx ? e1f : w1f;
        const int m = mtile * 16 + colm;
        union { unsigned short us[8]; uint4 v; } u;
#pragma unroll
        for (int i = 0; i < 8; ++i) u.us[i] = f2bf(srcD[m * 17 + tql * 8 + i]);
        const size_t off = ((size_t)(mtile * 1024 + ttile * 2 + tql) * 16 + colm) * 8;
        *(uint4*)(dst + off) = u.v;
    }
#pragma unroll
    for (int r = 0; r < 4; ++r) {
        float e = esA[r], wl = wlA[r];
#pragma unroll
        for (int off = 1; off < 16; off <<= 1) {
            e += __shfl_xor(e, off);
            wl += __shfl_xor(wl, off);
        }
        if (col == 0) {
            const int m = w * 16 + quad * 4 + r;
            EsPart[(size_t)m * 512 + ttile] = e;
            WaPart[(size_t)m * 512 + ttile] = wl;
        }
    }
}

// Stage 2 (MFMA): grid (14 dtiles, 32 k-splits of 256 t). Wave w = mtile.
// All four frag streams contiguous coalesced, depth-2 prefetch. R7 Pbuf layout.
__global__ __launch_bounds__(256) void k_stage2(
    const unsigned short* __restrict__ w1f, const unsigned short* __restrict__ e1f,
    const unsigned short* __restrict__ XfT, const unsigned short* __restrict__ JfT,
    float* __restrict__ Pbuf) {
    const int tid = threadIdx.x;
    const int lane = tid & 63;
    const int w = tid >> 6;                // mtile
    const int col = lane & 15, quad = lane >> 4;
    const int dt = blockIdx.x;
    const int by = blockIdx.y;

    const unsigned short* awp = w1f + ((size_t)(w * 1024 + by * 32 + quad) * 16 + col) * 8;
    const unsigned short* aep = e1f + ((size_t)(w * 1024 + by * 32 + quad) * 16 + col) * 8;
    const unsigned short* bxp = XfT + ((size_t)(dt * 1024 + by * 32 + quad) * 16 + col) * 8;
    const unsigned short* bjp = JfT + ((size_t)(dt * 1024 + by * 32 + quad) * 16 + col) * 8;

    bf8 aw[2], ae[2], bx[2], bj[2];
    aw[0] = *(const bf8*)awp;         ae[0] = *(const bf8*)aep;
    bx[0] = *(const bf8*)bxp;         bj[0] = *(const bf8*)bjp;
    aw[1] = *(const bf8*)(awp + 512); ae[1] = *(const bf8*)(aep + 512);
    bx[1] = *(const bf8*)(bxp + 512); bj[1] = *(const bf8*)(bjp + 512);

    f4 dA = {0.f, 0.f, 0.f, 0.f};
    f4 dB = {0.f, 0.f, 0.f, 0.f};
#pragma unroll
    for (int kk = 0; kk < 8; ++kk) {
        const int s = kk & 1;
        dA = __builtin_amdgcn_mfma_f32_16x16x32_bf16(aw[s], bx[s], dA, 0, 0, 0);
        dB = __builtin_amdgcn_mfma_f32_16x16x32_bf16(ae[s], bj[s], dB, 0, 0, 0);
        if (kk < 6) {
            aw[s] = *(const bf8*)(awp + (kk + 2) * 512);
            ae[s] = *(const bf8*)(aep + (kk + 2) * 512);
            bx[s] = *(const bf8*)(bxp + (kk + 2) * 512);
            bj[s] = *(const bf8*)(bjp + (kk + 2) * 512);
        }
    }
    // Pbuf[ks][mat][m][224]; lane stores D[m=w*16+quad*4+r][d=dt*16+col]
    float* p = Pbuf + (size_t)by * 28672 + dt * 16 + col;
#pragma unroll
    for (int r = 0; r < 4; ++r) {
        const int m = w * 16 + quad * 4 + r;
        p[m * DP] = dA[r];
        p[14336 + m * DP] = dB[r];
    }
}

// grid 112 x 256: AB[o] = sum_ks Pbuf[ks][o], o < 28672 (coalesced per slice)
__global__ void k_reduce(const float* __restrict__ P, float* __restrict__ AB) {
    const int o = blockIdx.x * 256 + threadIdx.x;
    float s = 0.0f;
#pragma unroll 8
    for (int ks = 0; ks < KS2; ++ks) s += P[(size_t)ks * 28672 + o];
    AB[o] = s;
}

// grid 64 (m) x 256: Es/Wa partial reduce + expand_tril + force contraction + Es
__global__ void k_final(const float* __restrict__ Rs, const float* __restrict__ qxsG,
                        const float* __restrict__ AB, const float* __restrict__ EsPart,
                        const float* __restrict__ WaPart, float* __restrict__ out) {
    int m = blockIdx.x, tid = threadIdx.x;
    __shared__ float R[NA * 3];
    __shared__ float Ff[NA][NA];
    __shared__ float redE[256];
    __shared__ float redW[256];
    if (tid < NA * 3) R[tid] = Rs[m * NA * 3 + tid];
    if (tid < NA) Ff[tid][tid] = 0.0f;
    {   // contiguous per-m partials: two floats per thread
        const float2 ep = ((const float2*)(EsPart + (size_t)m * 512))[tid];
        const float2 wp = ((const float2*)(WaPart + (size_t)m * 512))[tid];
        redE[tid] = ep.x + ep.y;
        redW[tid] = wp.x + wp.y;
    }
    __syncthreads();
    for (int s = 128; s > 0; s >>= 1) {
        if (tid < s) {
            redE[tid] += redE[tid + s];
            redW[tid] += redW[tid + s];
        }
        __syncthreads();
    }
    const float Wa = redW[0];
    if (tid < ND) {
        int i, j; d_to_ij(tid, i, j);
        float dx = R[i * 3] - R[j * 3];
        float dy = R[i * 3 + 1] - R[j * 3 + 1];
        float dz = R[i * 3 + 2] - R[j * 3 + 2];
        float dist2 = dx * dx + dy * dy + dz * dz;
        float fsx = qxsG[(tid >> 2) * 256 + m * 4 + (tid & 3)] * Wa
                  - AB[(size_t)m * DP + tid]
                  - AB[14336 + (size_t)m * DP + tid];
        float f = fsx / (dist2 * sqrtf(dist2));
        Ff[i][j] = f;
        Ff[j][i] = f;
    }
    __syncthreads();
    if (tid < NA * 3) {
        int a = tid / 3, c = tid % 3;
        float s = 0.0f;
        for (int b = 0; b < NA; ++b) {
            if (b == a) continue;
            s += Ff[a][b] * (R[a * 3 + c] - R[b * 3 + c]);
        }
        out[NM + m * NA * 3 + tid] = s;
    }
    if (tid == 0) out[m] = redE[0] / QC;
}

extern "C" void kernel_launch(void* const* d_in, const int* in_sizes, int n_in,
                              void* d_out, int out_size, void* d_ws, size_t ws_size,
                              hipStream_t stream) {
    const float* Rs = (const float*)d_in[0];
    const float* xs_train = (const float*)d_in[1];
    const float* Jx_alphas = (const float*)d_in[2];
    float* out = (float*)d_out;
    float* ws = (float*)d_ws;

    unsigned short* Xf  = (unsigned short*)(ws + O_XF);
    unsigned short* Jf  = (unsigned short*)(ws + O_JF);
    unsigned short* XfT = (unsigned short*)(ws + O_XFT);
    unsigned short* JfT = (unsigned short*)(ws + O_JFT);
    unsigned short* w1f = (unsigned short*)(ws + O_W1);
    unsigned short* e1f = (unsigned short*)(ws + O_E1);
    unsigned short* Af  = (unsigned short*)(ws + O_AF);
    float* qxsG   = ws + O_QG;
    float* nt     = ws + O_NTT;
    float* cJ     = ws + O_CJ;
    float* nx     = ws + O_NX;
    float* ABf    = ws + O_AB;
    float* Pbuf   = ws + O_PB;
    float* EsPart = ws + O_ESP;
    float* WaPart = ws + O_WAP;

    k_prep<<<832, 256, 0, stream>>>(Rs, xs_train, Jx_alphas, Xf, Jf, XfT, JfT,
                                    Af, qxsG, nx, nt, cJ);
    k_stage1<<<512, 256, 0, stream>>>(Af, Xf, Jf, nt, cJ, nx, w1f, e1f, EsPart, WaPart);
    k_stage2<<<dim3(14, KS2), 256, 0, stream>>>(w1f, e1f, XfT, JfT, Pbuf);
    k_reduce<<<112, 256, 0, stream>>>(Pbuf, ABf);
    k_final<<<NM, 256, 0, stream>>>(Rs, qxsG, ABf, EsPart, WaPart, out);
}

// Round 10
// 92.009 us; speedup vs baseline: 1.5541x; 1.0021x over previous
//
#include <hip/hip_runtime.h>
#include <math.h>

#define NA   21
#define NM   64
#define ND   210
#define DP   224            // padded descriptor row
#define NT   8192
#define NCH  28             // 8-wide k-chunks per descriptor row (224/8)
#define KS2  32             // stage2 K-splits (256 t each)

#define QC 0.22360679774997896f   // sqrt(5)/10
#define KE 0.016666666666666666f  // 5/(3*sig^2)

typedef short bf8 __attribute__((ext_vector_type(8)));   // 8 bf16 (4 VGPRs)
typedef float f4  __attribute__((ext_vector_type(4)));   // 4 fp32 acc

// ---- workspace layout (float offsets); bf16 arrays count elems/2 ----
// Xf/Jf  : stage1 B frags [ttile 512][kq 28][col_t 16][8 d]
// XfT/JfT: stage2 B frags [dtile 14][tq 1024][col_d 16][8 t]
// w1f/e1f: stage2 A frags [mtile 4][tq 1024][col_m 16][8 t]
// Af     : stage1 A frags [mtile 4][kq 28][col_m 16][8 d]
// Pbuf   : [ks 32][mat 2][m 64][d 224] fp32
// EsPart/WaPart: [m 64][ttile 512] fp32
#define O_XF   0u
#define O_JF   917504u
#define O_XFT  1835008u
#define O_JFT  2752512u
#define O_W1   3670016u
#define O_E1   3932160u
#define O_AF   4194304u
#define O_QG   4201472u        // qxsG fp32 [56][64][4]
#define O_NTT  4215808u        // nt [8192]
#define O_CJ   4224000u        // cJ [8192]
#define O_NX   4232192u        // [64]
#define O_PB   4261056u        // 917504 floats
#define O_ESP  5178560u        // [64][512]
#define O_WAP  5211328u        // [64][512] (end 5244096 = 21 MB)

__device__ __forceinline__ unsigned short f2bf(float f) {
    unsigned u = __float_as_uint(f);
    u += 0x7fffu + ((u >> 16) & 1u);
    return (unsigned short)(u >> 16);
}
__device__ __forceinline__ float bf2f(unsigned short h) {
    return __uint_as_float((unsigned)h << 16);
}

__device__ __forceinline__ void d_to_ij(int d, int& i, int& j) {
    int ii = (int)((1.0f + sqrtf(1.0f + 8.0f * (float)d)) * 0.5f);
    while (ii * (ii - 1) / 2 > d) --ii;
    while ((ii + 1) * ii / 2 <= d) ++ii;
    i = ii;
    j = d - ii * (ii - 1) / 2;
}

// Fused prep. Roles by blockIdx.x:
//  [0,512)   16 contiguous rows via LDS -> stage1-B frags + stage2-B(T) frags
//            + rowstats. xs/Jx each read exactly ONCE.
//  [512,576) geom -> Af, qxsG, nx
__global__ __launch_bounds__(256) void k_prep(
    const float* __restrict__ Rs, const float* __restrict__ xs,
    const float* __restrict__ Jx,
    unsigned short* __restrict__ Xf, unsigned short* __restrict__ Jf,
    unsigned short* __restrict__ XfT, unsigned short* __restrict__ JfT,
    unsigned short* __restrict__ Af, float* __restrict__ qxsG,
    float* __restrict__ nx, float* __restrict__ nt, float* __restrict__ cJ) {
    const int b = blockIdx.x, tid = threadIdx.x;
    __shared__ float lds[2 * 16 * 210];    // 26880 B

    if (b < 512) {
        const int t0 = b * 16;
        const float4* sx = (const float4*)(xs + (size_t)t0 * ND);
        const float4* sj = (const float4*)(Jx + (size_t)t0 * ND);
#pragma unroll
        for (int k = 0; k < 4; ++k) {      // 840 float4 per array
            const int i = k * 256 + tid;
            if (i < 840) {
                ((float4*)lds)[i] = sx[i];
                ((float4*)(lds + 3360))[i] = sj[i];
            }
        }
        __syncthreads();
        // 1792 frag chunks: [0,896) stage1-B, [896,1792) stage2-B(T)
#pragma unroll
        for (int k = 0; k < 7; ++k) {
            const int idx = k * 256 + tid;
            if (idx < 896) {               // stage1-B: (arr, kq, colt)
                const int arr = idx / 448;
                const int rem = idx - arr * 448;
                const int kq = rem >> 4, colt = rem & 15;
                const float* src = lds + arr * 3360 + colt * 210;
                const float sc = arr ? 1.0f : QC;
                union { unsigned short us[8]; uint4 v; } u;
#pragma unroll
                for (int i = 0; i < 8; ++i) {
                    const int d = kq * 8 + i;
                    u.us[i] = (d < ND) ? f2bf(sc * src[d]) : (unsigned short)0;
                }
                *(uint4*)((arr ? Jf : Xf) + ((size_t)(b * NCH + kq) * 16 + colt) * 8) = u.v;
            } else {                       // stage2-B(T): (arr, dtile, tql, col)
                const int idx2 = idx - 896;
                const int arr = idx2 / 448;
                const int rem = idx2 - arr * 448;
                const int dtile = rem >> 5;
                const int rem2 = rem & 31;
                const int tql = rem2 >> 4, col = rem2 & 15;
                const int d = dtile * 16 + col;
                const float* src = lds + arr * 3360 + tql * 8 * 210;
                const float sc = arr ? 1.0f : QC;
                union { unsigned short us[8]; uint4 v; } u;
#pragma unroll
                for (int i = 0; i < 8; ++i)
                    u.us[i] = (d < ND) ? f2bf(sc * src[i * 210 + d])
                                       : (unsigned short)0;
                const size_t off = ((size_t)(dtile * 1024 + b * 2 + tql) * 16 + col) * 8;
                *(uint4*)((arr ? JfT : XfT) + off) = u.v;
            }
        }
        // rowstats from LDS (rounded-consistent)
        const int tt = tid >> 4, l = tid & 15;
        const float* xr = lds + tt * 210;
        const float* jr = lds + 3360 + tt * 210;
        float sn = 0.0f, sc2 = 0.0f;
        for (int c = l; c < ND; c += 16) {
            float x = bf2f(f2bf(QC * xr[c]));
            float j = bf2f(f2bf(jr[c]));
            sn = fmaf(x, x, sn);
            sc2 = fmaf(x, j, sc2);
        }
#pragma unroll
        for (int off = 1; off < 16; off <<= 1) {
            sn += __shfl_xor(sn, off);
            sc2 += __shfl_xor(sc2, off);
        }
        if (l == 0) {
            nt[t0 + tt] = sn;
            cJ[t0 + tt] = sc2;
        }
    } else {                               // ---- geom: m = b-512
        const int m = b - 512;
        float* R = lds;
        float* red = lds + 64;
        if (tid < NA * 3) R[tid] = Rs[m * NA * 3 + tid];
        __syncthreads();
        float local = 0.0f;
        if (tid < DP) {
            float vr = 0.0f;
            unsigned short hv = 0;
            if (tid < ND) {
                int i, j; d_to_ij(tid, i, j);
                float dx = R[i * 3] - R[j * 3];
                float dy = R[i * 3 + 1] - R[j * 3 + 1];
                float dz = R[i * 3 + 2] - R[j * 3 + 2];
                float v = QC / sqrtf(dx * dx + dy * dy + dz * dz);
                hv = f2bf(v);
                vr = bf2f(hv);
            }
            Af[(((m >> 4) * NCH + (tid >> 3)) * 16 + (m & 15)) * 8 + (tid & 7)] = hv;
            qxsG[(tid >> 2) * 256 + m * 4 + (tid & 3)] = vr;
            local = vr * vr;
        }
        red[tid] = local;
        __syncthreads();
        for (int s = 128; s > 0; s >>= 1) {
            if (tid < s) red[tid] += red[tid + s];
            __syncthreads();
        }
        if (tid == 0) nx[m] = red[0];
    }
}

// Stage 1 (MFMA): grid 512 (1 ttile of 16 t). Wave w = mtile. A panel in regs;
// B frags contiguous coalesced 1-KB loads, depth-2 prefetch. No global atomics.
__global__ __launch_bounds__(256) void k_stage1(
    const unsigned short* __restrict__ Af, const unsigned short* __restrict__ Xf,
    const unsigned short* __restrict__ Jf, const float* __restrict__ nt,
    const float* __restrict__ cJ, const float* __restrict__ nx,
    unsigned short* __restrict__ w1f, unsigned short* __restrict__ e1f,
    float* __restrict__ EsPart, float* __restrict__ WaPart) {
    const int tid = threadIdx.x;
    const int lane = tid & 63;
    const int w = tid >> 6;                // mtile
    const int col = lane & 15, quad = lane >> 4;
    const int ttile = blockIdx.x;
    __shared__ float Dw[64][17];
    __shared__ float De[64][17];

    const unsigned short* ap = Af + ((size_t)(w * NCH + quad) * 16 + col) * 8;
    const unsigned short* xp = Xf + ((size_t)(ttile * NCH + quad) * 16 + col) * 8;
    const unsigned short* jp = Jf + ((size_t)(ttile * NCH + quad) * 16 + col) * 8;

    bf8 af[7];
#pragma unroll
    for (int kc = 0; kc < 7; ++kc) af[kc] = *(const bf8*)(ap + kc * 512);

    bf8 bx[2], bj[2];
    bx[0] = *(const bf8*)xp;
    bj[0] = *(const bf8*)jp;
    bx[1] = *(const bf8*)(xp + 512);
    bj[1] = *(const bf8*)(jp + 512);

    f4 c1 = {0.f, 0.f, 0.f, 0.f};
    f4 c2 = {0.f, 0.f, 0.f, 0.f};
#pragma unroll
    for (int kc = 0; kc < 7; ++kc) {
        const int s = kc & 1;
        c1 = __builtin_amdgcn_mfma_f32_16x16x32_bf16(af[kc], bx[s], c1, 0, 0, 0);
        c2 = __builtin_amdgcn_mfma_f32_16x16x32_bf16(af[kc], bj[s], c2, 0, 0, 0);
        if (kc < 5) {
            bx[s] = *(const bf8*)(xp + (kc + 2) * 512);
            bj[s] = *(const bf8*)(jp + (kc + 2) * 512);
        }
    }

    // epilogue: lane holds D[m=w*16+quad*4+r][t=ttile*16+col]
    const int t = ttile * 16 + col;
    const float ntv = nt[t], cjv = cJ[t];
    float esA[4], wlA[4];
#pragma unroll
    for (int r = 0; r < 4; ++r) {
        const int m = w * 16 + quad * 4 + r;
        float sq = fmaxf(nx[m] - 2.0f * c1[r] + ntv, 0.0f);
        float xd = sqrtf(sq);
        float e = KE * expf(-xd);
        float dotv = c2[r] - cjv;
        float wv = e * dotv;
        float ev = e * (1.0f + xd);
        Dw[m][col] = wv;
        De[m][col] = ev;
        esA[r] = ev * dotv;
        wlA[r] = wv;
    }
    __syncthreads();
    {   // coalesced frag-layout stores: 128 chunks per array
        const int aidx = tid >> 7;
        const int c = tid & 127;
        const int mtile = c >> 5, tql = (c >> 4) & 1, colm = c & 15;
        const float* srcD = aidx ? &De[0][0] : &Dw[0][0];
        unsigned short* dst = aidx ? e1f : w1f;
        const int m = mtile * 16 + colm;
        union { unsigned short us[8]; uint4 v; } u;
#pragma unroll
        for (int i = 0; i < 8; ++i) u.us[i] = f2bf(srcD[m * 17 + tql * 8 + i]);
        const size_t off = ((size_t)(mtile * 1024 + ttile * 2 + tql) * 16 + colm) * 8;
        *(uint4*)(dst + off) = u.v;
    }
#pragma unroll
    for (int r = 0; r < 4; ++r) {
        float e = esA[r], wl = wlA[r];
#pragma unroll
        for (int off = 1; off < 16; off <<= 1) {
            e += __shfl_xor(e, off);
            wl += __shfl_xor(wl, off);
        }
        if (col == 0) {
            const int m = w * 16 + quad * 4 + r;
            EsPart[(size_t)m * 512 + ttile] = e;
            WaPart[(size_t)m * 512 + ttile] = wl;
        }
    }
}

// Stage 2 (MFMA): grid (14 dtiles, 32 k-splits of 256 t). Wave w = mtile.
// All four frag streams contiguous coalesced, depth-2 prefetch.
__global__ __launch_bounds__(256) void k_stage2(
    const unsigned short* __restrict__ w1f, const unsigned short* __restrict__ e1f,
    const unsigned short* __restrict__ XfT, const unsigned short* __restrict__ JfT,
    float* __restrict__ Pbuf) {
    const int tid = threadIdx.x;
    const int lane = tid & 63;
    const int w = tid >> 6;                // mtile
    const int col = lane & 15, quad = lane >> 4;
    const int dt = blockIdx.x;
    const int by = blockIdx.y;

    const unsigned short* awp = w1f + ((size_t)(w * 1024 + by * 32 + quad) * 16 + col) * 8;
    const unsigned short* aep = e1f + ((size_t)(w * 1024 + by * 32 + quad) * 16 + col) * 8;
    const unsigned short* bxp = XfT + ((size_t)(dt * 1024 + by * 32 + quad) * 16 + col) * 8;
    const unsigned short* bjp = JfT + ((size_t)(dt * 1024 + by * 32 + quad) * 16 + col) * 8;

    bf8 aw[2], ae[2], bx[2], bj[2];
    aw[0] = *(const bf8*)awp;         ae[0] = *(const bf8*)aep;
    bx[0] = *(const bf8*)bxp;         bj[0] = *(const bf8*)bjp;
    aw[1] = *(const bf8*)(awp + 512); ae[1] = *(const bf8*)(aep + 512);
    bx[1] = *(const bf8*)(bxp + 512); bj[1] = *(const bf8*)(bjp + 512);

    f4 dA = {0.f, 0.f, 0.f, 0.f};
    f4 dB = {0.f, 0.f, 0.f, 0.f};
#pragma unroll
    for (int kk = 0; kk < 8; ++kk) {
        const int s = kk & 1;
        dA = __builtin_amdgcn_mfma_f32_16x16x32_bf16(aw[s], bx[s], dA, 0, 0, 0);
        dB = __builtin_amdgcn_mfma_f32_16x16x32_bf16(ae[s], bj[s], dB, 0, 0, 0);
        if (kk < 6) {
            aw[s] = *(const bf8*)(awp + (kk + 2) * 512);
            ae[s] = *(const bf8*)(aep + (kk + 2) * 512);
            bx[s] = *(const bf8*)(bxp + (kk + 2) * 512);
            bj[s] = *(const bf8*)(bjp + (kk + 2) * 512);
        }
    }
    // Pbuf[ks][mat][m][224]; lane stores D[m=w*16+quad*4+r][d=dt*16+col]
    float* p = Pbuf + (size_t)by * 28672 + dt * 16 + col;
#pragma unroll
    for (int r = 0; r < 4; ++r) {
        const int m = w * 16 + quad * 4 + r;
        p[m * DP] = dA[r];
        p[14336 + m * DP] = dB[r];
    }
}

// grid 64 (m) x 256: fused Pbuf ks-reduction + Es/Wa partial reduce +
// expand_tril + force contraction + Es
__global__ void k_final(const float* __restrict__ Rs, const float* __restrict__ qxsG,
                        const float* __restrict__ Pbuf, const float* __restrict__ EsPart,
                        const float* __restrict__ WaPart, float* __restrict__ out) {
    int m = blockIdx.x, tid = threadIdx.x;
    __shared__ float R[NA * 3];
    __shared__ float Ff[NA][NA];
    __shared__ float redE[256];
    __shared__ float redW[256];
    __shared__ float ABs[DP];
    if (tid < NA * 3) R[tid] = Rs[m * NA * 3 + tid];
    if (tid < NA) Ff[tid][tid] = 0.0f;
    if (tid < DP) {   // ks-reduction: 64 independent loads, fully unrolled
        const float* p0 = Pbuf + (size_t)m * DP + tid;
        float s1 = 0.0f, s2 = 0.0f;
#pragma unroll
        for (int ks = 0; ks < KS2; ++ks) {
            s1 += p0[(size_t)ks * 28672];
            s2 += p0[(size_t)ks * 28672 + 14336];
        }
        ABs[tid] = s1 + s2;
    }
    {   // contiguous per-m Es/Wa partials
        const float2 ep = ((const float2*)(EsPart + (size_t)m * 512))[tid];
        const float2 wp = ((const float2*)(WaPart + (size_t)m * 512))[tid];
        redE[tid] = ep.x + ep.y;
        redW[tid] = wp.x + wp.y;
    }
    __syncthreads();
    for (int s = 128; s > 0; s >>= 1) {
        if (tid < s) {
            redE[tid] += redE[tid + s];
            redW[tid] += redW[tid + s];
        }
        __syncthreads();
    }
    const float Wa = redW[0];
    if (tid < ND) {
        int i, j; d_to_ij(tid, i, j);
        float dx = R[i * 3] - R[j * 3];
        float dy = R[i * 3 + 1] - R[j * 3 + 1];
        float dz = R[i * 3 + 2] - R[j * 3 + 2];
        float dist2 = dx * dx + dy * dy + dz * dz;
        float fsx = qxsG[(tid >> 2) * 256 + m * 4 + (tid & 3)] * Wa - ABs[tid];
        float f = fsx / (dist2 * sqrtf(dist2));
        Ff[i][j] = f;
        Ff[j][i] = f;
    }
    __syncthreads();
    if (tid < NA * 3) {
        int a = tid / 3, c = tid % 3;
        float s = 0.0f;
        for (int b = 0; b < NA; ++b) {
            if (b == a) continue;
            s += Ff[a][b] * (R[a * 3 + c] - R[b * 3 + c]);
        }
        out[NM + m * NA * 3 + tid] = s;
    }
    if (tid == 0) out[m] = redE[0] / QC;
}

extern "C" void kernel_launch(void* const* d_in, const int* in_sizes, int n_in,
                              void* d_out, int out_size, void* d_ws, size_t ws_size,
                              hipStream_t stream) {
    const float* Rs = (const float*)d_in[0];
    const float* xs_train = (const float*)d_in[1];
    const float* Jx_alphas = (const float*)d_in[2];
    float* out = (float*)d_out;
    float* ws = (float*)d_ws;

    unsigned short* Xf  = (unsigned short*)(ws + O_XF);
    unsigned short* Jf  = (unsigned short*)(ws + O_JF);
    unsigned short* XfT = (unsigned short*)(ws + O_XFT);
    unsigned short* JfT = (unsigned short*)(ws + O_JFT);
    unsigned short* w1f = (unsigned short*)(ws + O_W1);
    unsigned short* e1f = (unsigned short*)(ws + O_E1);
    unsigned short* Af  = (unsigned short*)(ws + O_AF);
    float* qxsG   = ws + O_QG;
    float* nt     = ws + O_NTT;
    float* cJ     = ws + O_CJ;
    float* nx     = ws + O_NX;
    float* Pbuf   = ws + O_PB;
    float* EsPart = ws + O_ESP;
    float* WaPart = ws + O_WAP;

    k_prep<<<576, 256, 0, stream>>>(Rs, xs_train, Jx_alphas, Xf, Jf, XfT, JfT,
                                    Af, qxsG, nx, nt, cJ);
    k_stage1<<<512, 256, 0, stream>>>(Af, Xf, Jf, nt, cJ, nx, w1f, e1f, EsPart, WaPart);
    k_stage2<<<dim3(14, KS2), 256, 0, stream>>>(w1f, e1f, XfT, JfT, Pbuf);
    k_final<<<NM, 256, 0, stream>>>(Rs, qxsG, Pbuf, EsPart, WaPart, out);
}